// Round 11
// baseline (573.812 us; speedup 1.0000x reference)
//
#include <hip/hip_runtime.h>
#include <math.h>

#define B_TOT   262144ll
#define LOG_OFF 26214400ll   // delta = B*5*20
#define A_OFF   27262976ll   // + B*4

// workspace float offsets
#define WS_A4   0     // 4*25 softmaxed adjacencies
#define WS_ENCB 112   // 4*32 encoder bias per emotion (enc_b + e@enc_w[20:])

__device__ __forceinline__ void fma4(float a, const float4& w, float* acc) {
    acc[0] = fmaf(a, w.x, acc[0]);
    acc[1] = fmaf(a, w.y, acc[1]);
    acc[2] = fmaf(a, w.z, acc[2]);
    acc[3] = fmaf(a, w.w, acc[3]);
}

// ---------- precompute: 4 adjacency matrices + 4 encoder bias vectors ----------
__global__ void __launch_bounds__(128) precomp_kernel(
    const float* __restrict__ emo_emb, const float* __restrict__ A_w1,
    const float* __restrict__ A_b1, const float* __restrict__ A_w2,
    const float* __restrict__ A_b2, const float* __restrict__ enc_w,
    const float* __restrict__ enc_b, float* __restrict__ wsf)
{
    __shared__ float hid[4][32];
    __shared__ float av[4][25];
    const int t = threadIdx.x;
    const int c = t >> 5, m = t & 31;

    float acc = A_b1[m];
    #pragma unroll
    for (int k = 0; k < 16; ++k)
        acc = fmaf(emo_emb[c*16 + k], A_w1[k*32 + m], acc);
    hid[c][m] = fmaxf(acc, 0.f);
    __syncthreads();

    if (m < 25) {
        float a2 = A_b2[m];
        #pragma unroll
        for (int k = 0; k < 32; ++k)
            a2 = fmaf(hid[c][k], A_w2[k*25 + m], a2);
        av[c][m] = a2;
    }
    __syncthreads();

    if (m < 5) {
        float v[5];
        #pragma unroll
        for (int q = 0; q < 5; ++q) v[q] = av[c][m*5 + q];
        float mx = v[0];
        #pragma unroll
        for (int q = 1; q < 5; ++q) mx = fmaxf(mx, v[q]);
        float ssum = 0.f;
        #pragma unroll
        for (int q = 0; q < 5; ++q) { v[q] = expf(v[q] - mx); ssum += v[q]; }
        float inv = 1.f / ssum;
        #pragma unroll
        for (int q = 0; q < 5; ++q) wsf[WS_A4 + c*25 + m*5 + q] = v[q] * inv;
    }

    float eb = enc_b[m];
    #pragma unroll
    for (int k = 0; k < 16; ++k)
        eb = fmaf(emo_emb[c*16 + k], enc_w[(20 + k)*32 + m], eb);
    wsf[WS_ENCB + c*32 + m] = eb;
}

// ---------- main: lane = batch; all 5 nodes in-register, no cross-lane ----------
// 262144 = 1024 blocks * 256 threads exactly -> every lane active, no guards.
// Weights via uniform SGPR loads (proven R6/R8); only A4 table in LDS (400 B).
__global__ void __launch_bounds__(256, 2) main_kernel(
    const float* __restrict__ nf, const int* __restrict__ emo_idx,
    const float* __restrict__ enc_w, const float* __restrict__ ln_g,
    const float* __restrict__ ln_b, const float* __restrict__ w1,
    const float* __restrict__ b1, const float* __restrict__ w2,
    const float* __restrict__ b2, const float* __restrict__ clsw,
    const float* __restrict__ clsb, const float* __restrict__ wsf,
    float* __restrict__ out)
{
    __shared__ float sA4[100];
    const int tid = threadIdx.x;
    if (tid < 100) sA4[tid] = wsf[WS_A4 + tid];
    __syncthreads();

    const long long b = (long long)blockIdx.x * 256 + tid;
    const int emo = emo_idx[b];

    // uniform (SGPR) weight views
    const float4* encw4 = (const float4*)enc_w;   // rows 0..19 used
    const float4* w1_4  = (const float4*)w1;
    const float4* w2_4  = (const float4*)w2;
    const float4* b1_4  = (const float4*)b1;
    const float4* lg4   = (const float4*)ln_g;
    const float4* lb4   = (const float4*)ln_b;
    const float4* b2_4  = (const float4*)b2;
    const float4* cw4   = (const float4*)clsw;    // (160,4) row-major
    const float4  cb    = *(const float4*)clsb;

    // per-lane emotion encoder bias (L2-hot, 4 distinct lines)
    float eb[32];
    {
        const float4* ebp = (const float4*)(wsf + WS_ENCB + emo*32);
        #pragma unroll
        for (int j4 = 0; j4 < 8; ++j4) {
            float4 v = ebp[j4];
            eb[4*j4+0]=v.x; eb[4*j4+1]=v.y; eb[4*j4+2]=v.z; eb[4*j4+3]=v.w;
        }
    }

    // ---- phase 1: per node, encoder + LN + relu -> h[5][32] (all in registers) ----
    float h[5][32];
    const float4* xbase = (const float4*)(nf + b*100ll);
    #pragma unroll
    for (int n = 0; n < 5; ++n) {
        float x[20];
        #pragma unroll
        for (int t = 0; t < 5; ++t) {
            float4 v = xbase[n*5 + t];
            x[4*t+0]=v.x; x[4*t+1]=v.y; x[4*t+2]=v.z; x[4*t+3]=v.w;
        }
        float y[32];
        #pragma unroll
        for (int j = 0; j < 32; ++j) y[j] = eb[j];
        #pragma unroll
        for (int d = 0; d < 20; ++d) {
            float xv = x[d];
            #pragma unroll
            for (int j4 = 0; j4 < 8; ++j4)
                fma4(xv, encw4[d*8 + j4], y + 4*j4);
        }
        float sum = 0.f;
        #pragma unroll
        for (int j = 0; j < 32; ++j) sum += y[j];
        float mu = sum * 0.03125f;
        float sq = 0.f;
        #pragma unroll
        for (int j = 0; j < 32; ++j) { float d = y[j] - mu; sq = fmaf(d, d, sq); }
        float rs = rsqrtf(fmaf(sq, 0.03125f, 1e-5f));
        #pragma unroll
        for (int j4 = 0; j4 < 8; ++j4) {
            float4 gg = lg4[j4], bb = lb4[j4];
            h[n][4*j4+0] = fmaxf(fmaf((y[4*j4+0]-mu)*rs, gg.x, bb.x), 0.f);
            h[n][4*j4+1] = fmaxf(fmaf((y[4*j4+1]-mu)*rs, gg.y, bb.y), 0.f);
            h[n][4*j4+2] = fmaxf(fmaf((y[4*j4+2]-mu)*rs, gg.z, bb.z), 0.f);
            h[n][4*j4+3] = fmaxf(fmaf((y[4*j4+3]-mu)*rs, gg.w, bb.w), 0.f);
        }
    }

    // ---- phase 2: per output node i (rolled loop, registers static inside) ----
    float logits[4] = {cb.x, cb.y, cb.z, cb.w};
    for (int i = 0; i < 5; ++i) {
        float ai[5];
        #pragma unroll
        for (int nn = 0; nn < 5; ++nn) ai[nn] = sA4[emo*25 + i*5 + nn];
        #pragma unroll
        for (int nn = 0; nn < 5; ++nn)
            out[A_OFF + b*25ll + i*5 + nn] = ai[nn];

        // agg: hagg = sum_nn ai[nn] * h[nn][:]  (in-lane, static h indexing)
        float hagg[32];
        #pragma unroll
        for (int j = 0; j < 32; ++j) {
            float v = ai[0] * h[0][j];
            v = fmaf(ai[1], h[1][j], v);
            v = fmaf(ai[2], h[2][j], v);
            v = fmaf(ai[3], h[3][j], v);
            v = fmaf(ai[4], h[4][j], v);
            hagg[j] = v;
        }

        // cls partial (in-lane accumulate)
        #pragma unroll
        for (int j = 0; j < 32; ++j) {
            float hv = hagg[j];
            float4 w = cw4[i*32 + j];
            logits[0] = fmaf(hv, w.x, logits[0]);
            logits[1] = fmaf(hv, w.y, logits[1]);
            logits[2] = fmaf(hv, w.z, logits[2]);
            logits[3] = fmaf(hv, w.w, logits[3]);
        }

        // out1: r = relu(hagg @ w1 + b1)
        float r[32];
        #pragma unroll
        for (int j4 = 0; j4 < 8; ++j4) {
            float4 v = b1_4[j4];
            r[4*j4+0]=v.x; r[4*j4+1]=v.y; r[4*j4+2]=v.z; r[4*j4+3]=v.w;
        }
        #pragma unroll
        for (int k = 0; k < 32; ++k) {
            float hv = hagg[k];
            #pragma unroll
            for (int j4 = 0; j4 < 8; ++j4)
                fma4(hv, w1_4[k*8 + j4], r + 4*j4);
        }
        #pragma unroll
        for (int j = 0; j < 32; ++j) r[j] = fmaxf(r[j], 0.f);

        // out2: delta row, d4-outer to keep only 4 accumulators live
        float* orow = out + b*100ll + i*20;
        #pragma unroll
        for (int d4 = 0; d4 < 5; ++d4) {
            float4 acc = b2_4[d4];
            #pragma unroll
            for (int k = 0; k < 32; ++k) {
                float rv = r[k];
                float4 w = w2_4[k*5 + d4];
                acc.x = fmaf(rv, w.x, acc.x);
                acc.y = fmaf(rv, w.y, acc.y);
                acc.z = fmaf(rv, w.z, acc.z);
                acc.w = fmaf(rv, w.w, acc.w);
            }
            *(float4*)(orow + 4*d4) = acc;
        }
    }

    *(float4*)(out + LOG_OFF + b*4ll) =
        make_float4(logits[0], logits[1], logits[2], logits[3]);
}

extern "C" void kernel_launch(void* const* d_in, const int* in_sizes, int n_in,
                              void* d_out, int out_size, void* d_ws, size_t ws_size,
                              hipStream_t stream) {
    const float* nf      = (const float*)d_in[0];
    const int*   emo_idx = (const int*)  d_in[1];
    const float* emo_emb = (const float*)d_in[2];
    const float* A_w1    = (const float*)d_in[3];
    const float* A_b1    = (const float*)d_in[4];
    const float* A_w2    = (const float*)d_in[5];
    const float* A_b2    = (const float*)d_in[6];
    const float* enc_w   = (const float*)d_in[7];
    const float* enc_b   = (const float*)d_in[8];
    const float* ln_g    = (const float*)d_in[9];
    const float* ln_b    = (const float*)d_in[10];
    const float* out_w1  = (const float*)d_in[11];
    const float* out_b1  = (const float*)d_in[12];
    const float* out_w2  = (const float*)d_in[13];
    const float* out_b2  = (const float*)d_in[14];
    const float* cls_w   = (const float*)d_in[15];
    const float* cls_b   = (const float*)d_in[16];
    float* wsf = (float*)d_ws;
    float* outf = (float*)d_out;

    precomp_kernel<<<1, 128, 0, stream>>>(emo_emb, A_w1, A_b1, A_w2, A_b2,
                                          enc_w, enc_b, wsf);
    main_kernel<<<1024, 256, 0, stream>>>(nf, emo_idx, enc_w, ln_g, ln_b,
                                          out_w1, out_b1, out_w2, out_b2,
                                          cls_w, cls_b, wsf, outf);
}